// Round 1
// baseline (5068.824 us; speedup 1.0000x reference)
//
#include <hip/hip_runtime.h>
#include <hip/hip_bf16.h>

#define SS 13
#define P2 169    // 13*13
#define P4 28561  // 13^4

// ---------------------------------------------------------------------------
// conv4d: for fixed (b, hb, wb) compute all (co, ha, wa) outputs.
//   o[co,ha,wa] = sum_ci [ sum_taps w1[co,ci,t] * in(b,ci,ha+da,wa+dwa,hb,wb)
//                        + sum_taps w2[co,ci,t] * in(b,ci,ha,wa,hb+dh,wb+dw) ]
//                 + b1[co] + b2[co]
// Input is optionally pre-normalized on load: h = relu(v*A[b,ci] + C[b,ci]).
// Also accumulates per-(b,group) sum / sumsq of outputs into stats (atomics).
// ---------------------------------------------------------------------------
template<int CIN, int COUT, bool NORM_IN>
__global__ __launch_bounds__(256, 2) void conv4d_kernel(
    const float* __restrict__ in, const float* __restrict__ w1,
    const float* __restrict__ b1, const float* __restrict__ w2,
    const float* __restrict__ b2, const float* __restrict__ AC,
    float* __restrict__ y, float* __restrict__ stats)
{
    constexpr int CI_CHUNK = 8;
    __shared__ float tile[CI_CHUNK][9][176];

    const int hbwb = blockIdx.x;
    const int hb = hbwb / SS, wb = hbwb - hb * SS;
    const int b = blockIdx.y;
    const int co_blk = blockIdx.z * 64;
    const int t = threadIdx.x;
    const int lane = t & 63, wave = t >> 6;
    const int co0 = co_blk + wave * 16;

    float acc[16][3];
#pragma unroll
    for (int i = 0; i < 16; i++)
#pragma unroll
        for (int p = 0; p < 3; p++) acc[i][p] = 0.f;

    for (int ci0 = 0; ci0 < CIN; ci0 += CI_CHUNK) {
        __syncthreads();
        // ---- stage tile: [ci][9 neighbor (hb,wb)][169 (ha,wa)] ----
        for (int r = t; r < CI_CHUNK * P2; r += 256) {
            int cil = r / P2;
            int p = r - cil * P2;
            int ci = ci0 + cil;
            int ha = p / SS, wa = p - ha * SS;
            const float* src = in + ((((size_t)b * CIN + ci) * SS + ha) * SS + wa) * P2;
            float a = 1.f, cc = 0.f;
            if (NORM_IN) {
                a  = AC[(b * CIN + ci) * 2];
                cc = AC[(b * CIN + ci) * 2 + 1];
            }
#pragma unroll
            for (int j = 0; j < 9; j++) {
                int dh = j / 3 - 1, dw = j % 3 - 1;
                int hb2 = hb + dh, wb2 = wb + dw;
                float v = 0.f;
                if ((unsigned)hb2 < SS && (unsigned)wb2 < SS) {
                    v = src[hb2 * SS + wb2];
                    if (NORM_IN) v = fmaxf(v * a + cc, 0.f);
                }
                tile[cil][j][p] = v;
            }
        }
        __syncthreads();

        // ---- compute ----
        for (int cil = 0; cil < CI_CHUNK; cil++) {
            int ci = ci0 + cil;
            float v2[3][9], v1[3][9];
#pragma unroll
            for (int pp = 0; pp < 3; pp++) {
                int p = lane + 64 * pp;
                bool pv = p < P2;
                int ha = p / SS, wa = p - ha * SS;
#pragma unroll
                for (int j = 0; j < 9; j++) {
                    v2[pp][j] = pv ? tile[cil][j][p] : 0.f;
                    int da = j / 3 - 1, dwa = j % 3 - 1;
                    int ha2 = ha + da, wa2 = wa + dwa;
                    bool ok = pv && (unsigned)ha2 < SS && (unsigned)wa2 < SS;
                    v1[pp][j] = ok ? tile[cil][4][ha2 * SS + wa2] : 0.f;
                }
            }
            int cou = __builtin_amdgcn_readfirstlane(co0);
#pragma unroll
            for (int coi = 0; coi < 16; coi++) {
                int co = cou + coi;
                const float* wp1 = w1 + ((size_t)co * CIN + ci) * 9;
                const float* wp2 = w2 + ((size_t)co * CIN + ci) * 9;
#pragma unroll
                for (int j = 0; j < 9; j++) {
                    float wv1 = wp1[j], wv2 = wp2[j];
#pragma unroll
                    for (int pp = 0; pp < 3; pp++) {
                        acc[coi][pp] += wv1 * v1[pp][j];
                        acc[coi][pp] += wv2 * v2[pp][j];
                    }
                }
            }
        }
    }

    // ---- bias, store, per-(b,group) stats ----
    float s1 = 0.f, s2 = 0.f;
#pragma unroll
    for (int coi = 0; coi < 16; coi++) {
        int co = co0 + coi;
        float bias = b1[co] + b2[co];
#pragma unroll
        for (int pp = 0; pp < 3; pp++) {
            int p = lane + 64 * pp;
            if (p < P2) {
                float v = acc[coi][pp] + bias;
                y[(((size_t)b * COUT + co) * P2 + p) * P2 + hbwb] = v;
                s1 += v;
                s2 += v * v;
            }
        }
    }
    for (int off = 32; off; off >>= 1) {
        s1 += __shfl_down(s1, off);
        s2 += __shfl_down(s2, off);
    }
    if (lane == 0) {
        int grp = co0 / (COUT / 4);
        atomicAdd(&stats[(b * 4 + grp) * 2], s1);
        atomicAdd(&stats[(b * 4 + grp) * 2 + 1], s2);
    }
}

// ---------------------------------------------------------------------------
// Finalize group stats -> per-(b,channel) affine A,C:  h = relu(y*A + C)
// ---------------------------------------------------------------------------
template<int COUT>
__global__ void stats_fin(const float* __restrict__ stats,
                          const float* __restrict__ gs,
                          const float* __restrict__ gb,
                          float* __restrict__ AC)
{
    int i = threadIdx.x + blockIdx.x * blockDim.x;
    if (i >= 4 * COUT) return;
    int b = i / COUT, c = i - b * COUT;
    int grp = c / (COUT / 4);
    float cnt = (float)((COUT / 4) * P4);
    float s1 = stats[(b * 4 + grp) * 2];
    float s2 = stats[(b * 4 + grp) * 2 + 1];
    float mean = s1 / cnt;
    float var = s2 / cnt - mean * mean;
    float r = rsqrtf(var + 1e-5f);
    float A = r * gs[c];
    AC[i * 2] = A;
    AC[i * 2 + 1] = gb[c] - mean * A;
}

// ---------------------------------------------------------------------------
// out[b,co,ha,wa,hb] = mean_wb relu(y*A + C)
// ---------------------------------------------------------------------------
__global__ void mean_out_kernel(const float* __restrict__ y,
                                const float* __restrict__ AC,
                                float* __restrict__ out, int total)
{
    int idx = threadIdx.x + blockIdx.x * 256;
    if (idx >= total) return;
    int hb = idx % SS;
    int rest = idx / SS;        // (b*256+co)*169 + p
    int p = rest % P2;
    int bc = rest / P2;
    const float* src = y + ((size_t)bc * P2 + p) * P2 + hb * SS;
    float A = AC[bc * 2], C = AC[bc * 2 + 1];
    float s = 0.f;
#pragma unroll
    for (int w = 0; w < SS; w++) s += fmaxf(src[w] * A + C, 0.f);
    out[idx] = s * (1.f / SS);
}

extern "C" void kernel_launch(void* const* d_in, const int* in_sizes, int n_in,
                              void* d_out, int out_size, void* d_ws, size_t ws_size,
                              hipStream_t stream)
{
    const float* x = (const float*)d_in[0];
    const float* w1[3], *bb1[3], *w2[3], *bb2[3], *gs[3], *gb[3];
    for (int i = 0; i < 3; i++) {
        w1[i]  = (const float*)d_in[1 + 6 * i];
        bb1[i] = (const float*)d_in[2 + 6 * i];
        w2[i]  = (const float*)d_in[3 + 6 * i];
        bb2[i] = (const float*)d_in[4 + 6 * i];
        gs[i]  = (const float*)d_in[5 + 6 * i];
        gb[i]  = (const float*)d_in[6 + 6 * i];
    }
    float* out = (float*)d_out;
    float* ws = (float*)d_ws;

    float* stats0 = ws;        // 32 floats each
    float* stats1 = ws + 32;
    float* stats2 = ws + 64;
    float* AC0 = ws + 256;     // up to 2048 floats each
    float* AC1 = ws + 2304;
    float* AC2 = ws + 4352;
    float* y2 = ws + 8192;                        // 4*128*28561 = 14,623,232 floats
    float* y1 = y2 + (size_t)4 * 128 * P4;        // region shared by y1 (7.3M) / y3 (29.2M)
    float* y3 = y1;

    hipMemsetAsync(d_ws, 0, 8192 * sizeof(float), stream);

    conv4d_kernel<16, 64, false><<<dim3(P2, 4, 1), 256, 0, stream>>>(
        x, w1[0], bb1[0], w2[0], bb2[0], nullptr, y1, stats0);
    stats_fin<64><<<1, 256, 0, stream>>>(stats0, gs[0], gb[0], AC0);

    conv4d_kernel<64, 128, true><<<dim3(P2, 4, 2), 256, 0, stream>>>(
        y1, w1[1], bb1[1], w2[1], bb2[1], AC0, y2, stats1);
    stats_fin<128><<<2, 256, 0, stream>>>(stats1, gs[1], gb[1], AC1);

    conv4d_kernel<128, 256, true><<<dim3(P2, 4, 4), 256, 0, stream>>>(
        y2, w1[2], bb1[2], w2[2], bb2[2], AC1, y3, stats2);
    stats_fin<256><<<4, 256, 0, stream>>>(stats2, gs[2], gb[2], AC2);

    int total = 4 * 256 * P2 * SS;
    mean_out_kernel<<<(total + 255) / 256, 256, 0, stream>>>(y3, AC2, out, total);
}